// Round 10
// baseline (194.725 us; speedup 1.0000x reference)
//
#include <hip/hip_runtime.h>
#include <hip/hip_bf16.h>

#define DM 1024
#define DH 64
#define TT 2048

typedef __attribute__((ext_vector_type(8))) short bf16x8;
typedef __attribute__((ext_vector_type(4))) short s16x4;
typedef __attribute__((ext_vector_type(4))) float f32x4;

static __device__ __forceinline__ short f2bf(float f) {
  union { __hip_bfloat16 h; short s; } u;
  u.h = __float2bfloat16(f);
  return u.s;
}

// ---------------- kernel 1: W -> W^T bf16, layout [3][64 n][1024 k] ----------------
__global__ __launch_bounds__(256) void convw_kernel(const float* __restrict__ Wq,
                                                    const float* __restrict__ Wk,
                                                    const float* __restrict__ Wv,
                                                    short* __restrict__ Wt) {
  int idx = blockIdx.x * 256 + threadIdx.x;
  if (idx >= 3 * 64 * 1024) return;
  int wsel = idx >> 16;
  int rem  = idx & 65535;
  int n = rem >> 10;
  int k = rem & 1023;
  const float* W = (wsel == 0) ? Wq : (wsel == 1) ? Wk : Wv;
  Wt[idx] = f2bf(W[k * DH + n]);
}

// ---------------- kernel 2: projection as tiled GEMM (unchanged from r7/r8) -------
// Q outputs pre-scaled by 1/sqrt(DM).
__global__ __launch_bounds__(512, 4) void proj_kernel(const float* __restrict__ x,
                                                      const short* __restrict__ Wt,
                                                      short* __restrict__ Qb,
                                                      short* __restrict__ Kb,
                                                      short* __restrict__ Vt) {
  __shared__ short As[64 * 64];
  __shared__ short Bs[192 * 64];
  char* Ab = (char*)As;
  char* Bb = (char*)Bs;
  int tid  = threadIdx.x;
  int lane = tid & 63;
  int wid  = tid >> 6;
  int l15 = lane & 15, lq = lane >> 4;
  int wr = wid >> 1, wc = wid & 1;
  int row0 = blockIdx.x * 64;

  int arow = tid >> 3, acg = tid & 7;
  const float* axp = x + (size_t)(row0 + arow) * DM + acg * 8;
  int abyte = arow * 128 + ((acg * 16) ^ ((arow & 7) << 4));
  int brow = tid >> 1, bh = tid & 1;
  const short* bwp = Wt + (size_t)brow * DM + bh * 32;
  int bswz = (brow & 7) << 4;
  int bbyte[4];
  #pragma unroll
  for (int i = 0; i < 4; ++i) bbyte[i] = brow * 128 + ((bh * 64 + i * 16) ^ bswz);

  float4 pa0 = ((const float4*)axp)[0];
  float4 pa1 = ((const float4*)axp)[1];
  bf16x8 pb[4];
  if (tid < 384) {
    #pragma unroll
    for (int i = 0; i < 4; ++i) pb[i] = ((const bf16x8*)bwp)[i];
  }

  f32x4 acc[6];
  #pragma unroll
  for (int n = 0; n < 6; ++n) acc[n] = (f32x4){0.f, 0.f, 0.f, 0.f};

  for (int s = 0; s < 16; ++s) {
    bf16x8 aw;
    aw[0] = f2bf(pa0.x); aw[1] = f2bf(pa0.y); aw[2] = f2bf(pa0.z); aw[3] = f2bf(pa0.w);
    aw[4] = f2bf(pa1.x); aw[5] = f2bf(pa1.y); aw[6] = f2bf(pa1.z); aw[7] = f2bf(pa1.w);
    *(bf16x8*)(Ab + abyte) = aw;
    if (tid < 384) {
      #pragma unroll
      for (int i = 0; i < 4; ++i) *(bf16x8*)(Bb + bbyte[i]) = pb[i];
    }
    __syncthreads();
    if (s < 15) {
      const float* nax = axp + (s + 1) * 64;
      pa0 = ((const float4*)nax)[0];
      pa1 = ((const float4*)nax)[1];
      if (tid < 384) {
        const short* nbw = bwp + (s + 1) * 64;
        #pragma unroll
        for (int i = 0; i < 4; ++i) pb[i] = ((const bf16x8*)nbw)[i];
      }
    }
    #pragma unroll
    for (int kk = 0; kk < 2; ++kk) {
      int koff = (kk * 64 + lq * 16) ^ ((l15 & 7) << 4);
      bf16x8 af = *(const bf16x8*)(Ab + (wr * 16 + l15) * 128 + koff);
      bf16x8 bf[6];
      #pragma unroll
      for (int nc = 0; nc < 6; ++nc)
        bf[nc] = *(const bf16x8*)(Bb + (wc * 96 + nc * 16 + l15) * 128 + koff);
      #pragma unroll
      for (int nc = 0; nc < 6; ++nc)
        acc[nc] = __builtin_amdgcn_mfma_f32_16x16x32_bf16(af, bf[nc], acc[nc], 0, 0, 0);
    }
    __syncthreads();
  }

  int growb = row0 + wr * 16 + lq * 4;
  #pragma unroll
  for (int nc = 0; nc < 6; ++nc) {
    int gcolb = wc * 96 + nc * 16;
    int mat = gcolb >> 6;
    int mc  = (gcolb & 63) + l15;
    if (mat == 0) {
      #pragma unroll
      for (int r = 0; r < 4; ++r)
        Qb[(size_t)(growb + r) * DH + mc] = f2bf(acc[nc][r] * 0.03125f);
    } else if (mat == 1) {
      #pragma unroll
      for (int r = 0; r < 4; ++r)
        Kb[(size_t)(growb + r) * DH + mc] = f2bf(acc[nc][r]);
    } else {
      int b = growb >> 11;
      int tl = growb & 2047;
      s16x4 pk;
      #pragma unroll
      for (int r = 0; r < 4; ++r) pk[r] = f2bf(acc[nc][r]);
      *(s16x4*)(Vt + ((size_t)(b * DH + mc)) * TT + tl) = pk;
    }
  }
}

// ---------------- ABLATION: flash phases 1 (QK+mask+max) / 2 (+softmax) ----------
// Same structure/grid as production flash; no PV/LDS/merge. Results sunk to junk
// so nothing is DCE'd (mrow<-rmax<-all s<-all MFMA<-all loads; lrow<-exp'd s).
template<int PHASE>
__global__ __launch_bounds__(512) void flash_abl(const short* __restrict__ Qb,
                                                 const short* __restrict__ Kb,
                                                 float* __restrict__ junk) {
  int w    = threadIdx.x >> 6;
  int lane = threadIdx.x & 63;
  int l15 = lane & 15, lq = lane >> 4;
  int qt = 127 - (blockIdx.x >> 3);
  int b  = blockIdx.x & 7;
  int row0 = qt * 16;

  const short* qp = Qb + ((size_t)(b * TT + row0 + l15)) * DH + 8 * lq;
  bf16x8 qf0 = *reinterpret_cast<const bf16x8*>(qp);
  bf16x8 qf1 = *reinterpret_cast<const bf16x8*>(qp + 32);

  float mrow[4] = {-1e30f, -1e30f, -1e30f, -1e30f};
  float lrow[4] = {0.f, 0.f, 0.f, 0.f};

  int nkt = (qt >> 2) + 1;
  for (int kt = w; kt < nkt; kt += 8) {
    int k0 = kt * 64;
    f32x4 s[4];
    #pragma unroll
    for (int nt = 0; nt < 4; ++nt) s[nt] = (f32x4){0.f, 0.f, 0.f, 0.f};
    #pragma unroll
    for (int nt = 0; nt < 4; ++nt) {
      const short* kp = Kb + ((size_t)(b * TT + k0 + nt * 16 + l15)) * DH + 8 * lq;
      bf16x8 b0 = *reinterpret_cast<const bf16x8*>(kp);
      bf16x8 b1 = *reinterpret_cast<const bf16x8*>(kp + 32);
      s[nt] = __builtin_amdgcn_mfma_f32_16x16x32_bf16(qf0, b0, s[nt], 0, 0, 0);
      s[nt] = __builtin_amdgcn_mfma_f32_16x16x32_bf16(qf1, b1, s[nt], 0, 0, 0);
    }
    float rmax[4] = {-1e30f, -1e30f, -1e30f, -1e30f};
    #pragma unroll
    for (int nt = 0; nt < 4; ++nt) {
      int key = k0 + nt * 16 + l15;
      #pragma unroll
      for (int r = 0; r < 4; ++r) {
        int qr = row0 + lq * 4 + r;
        float v = s[nt][r];
        v = (key <= qr) ? v : -1e30f;
        s[nt][r] = v;
        rmax[r] = fmaxf(rmax[r], v);
      }
    }
    #pragma unroll
    for (int r = 0; r < 4; ++r)
      #pragma unroll
      for (int d = 1; d < 16; d <<= 1)
        rmax[r] = fmaxf(rmax[r], __shfl_xor(rmax[r], d));

    if constexpr (PHASE == 1) {
      #pragma unroll
      for (int r = 0; r < 4; ++r) mrow[r] = fmaxf(mrow[r], rmax[r]);
    } else {
      float alpha[4], rs[4];
      #pragma unroll
      for (int r = 0; r < 4; ++r) {
        float mn = fmaxf(mrow[r], rmax[r]);
        alpha[r] = __expf(mrow[r] - mn);
        mrow[r] = mn;
        rs[r] = 0.f;
      }
      #pragma unroll
      for (int nt = 0; nt < 4; ++nt)
        #pragma unroll
        for (int r = 0; r < 4; ++r) {
          float p = __expf(s[nt][r] - mrow[r]);
          s[nt][r] = p;
          rs[r] += p;
        }
      #pragma unroll
      for (int r = 0; r < 4; ++r) {
        #pragma unroll
        for (int d = 1; d < 16; d <<= 1)
          rs[r] += __shfl_xor(rs[r], d);
        lrow[r] = lrow[r] * alpha[r] + rs[r];
      }
    }
  }
  float v = mrow[0] + mrow[1] + mrow[2] + mrow[3] +
            lrow[0] + lrow[1] + lrow[2] + lrow[3];
  junk[(size_t)blockIdx.x * 512 + threadIdx.x] = v;
}

// ---------------- kernel 3: production flash (r7 8-way structure, prescaled Q) ----
__global__ __launch_bounds__(512) void flash_kernel(const short* __restrict__ Qb,
                                                    const short* __restrict__ Kb,
                                                    const short* __restrict__ Vt,
                                                    float* __restrict__ out) {
  __shared__ union ShBuf {
    short Pl[8][16][72];
    float Om[8][16][64];
  } sh;
  __shared__ float Mm[8][16];
  __shared__ float Lm[8][16];
  __shared__ float Sc[8][16];
  __shared__ float Linv[16];
  int w    = threadIdx.x >> 6;
  int lane = threadIdx.x & 63;
  int l15 = lane & 15, lq = lane >> 4;
  int qt = 127 - (blockIdx.x >> 3);
  int b  = blockIdx.x & 7;
  int row0 = qt * 16;

  const short* qp = Qb + ((size_t)(b * TT + row0 + l15)) * DH + 8 * lq;
  bf16x8 qf0 = *reinterpret_cast<const bf16x8*>(qp);
  bf16x8 qf1 = *reinterpret_cast<const bf16x8*>(qp + 32);

  float mrow[4] = {-1e30f, -1e30f, -1e30f, -1e30f};
  float lrow[4] = {0.f, 0.f, 0.f, 0.f};
  f32x4 o[4];
  #pragma unroll
  for (int nt = 0; nt < 4; ++nt) o[nt] = (f32x4){0.f, 0.f, 0.f, 0.f};

  int nkt = (qt >> 2) + 1;
  for (int kt = w; kt < nkt; kt += 8) {
    int k0 = kt * 64;
    f32x4 s[4];
    #pragma unroll
    for (int nt = 0; nt < 4; ++nt) s[nt] = (f32x4){0.f, 0.f, 0.f, 0.f};
    #pragma unroll
    for (int nt = 0; nt < 4; ++nt) {
      const short* kp = Kb + ((size_t)(b * TT + k0 + nt * 16 + l15)) * DH + 8 * lq;
      bf16x8 b0 = *reinterpret_cast<const bf16x8*>(kp);
      bf16x8 b1 = *reinterpret_cast<const bf16x8*>(kp + 32);
      s[nt] = __builtin_amdgcn_mfma_f32_16x16x32_bf16(qf0, b0, s[nt], 0, 0, 0);
      s[nt] = __builtin_amdgcn_mfma_f32_16x16x32_bf16(qf1, b1, s[nt], 0, 0, 0);
    }
    float rmax[4] = {-1e30f, -1e30f, -1e30f, -1e30f};
    #pragma unroll
    for (int nt = 0; nt < 4; ++nt) {
      int key = k0 + nt * 16 + l15;
      #pragma unroll
      for (int r = 0; r < 4; ++r) {
        int qr = row0 + lq * 4 + r;
        float v = s[nt][r];
        v = (key <= qr) ? v : -1e30f;
        s[nt][r] = v;
        rmax[r] = fmaxf(rmax[r], v);
      }
    }
    #pragma unroll
    for (int r = 0; r < 4; ++r)
      #pragma unroll
      for (int d = 1; d < 16; d <<= 1)
        rmax[r] = fmaxf(rmax[r], __shfl_xor(rmax[r], d));
    float alpha[4], rs[4];
    #pragma unroll
    for (int r = 0; r < 4; ++r) {
      float mn = fmaxf(mrow[r], rmax[r]);
      alpha[r] = __expf(mrow[r] - mn);
      mrow[r] = mn;
      rs[r] = 0.f;
    }
    #pragma unroll
    for (int nt = 0; nt < 4; ++nt)
      #pragma unroll
      for (int r = 0; r < 4; ++r) {
        float p = __expf(s[nt][r] - mrow[r]);
        s[nt][r] = p;
        rs[r] += p;
      }
    #pragma unroll
    for (int r = 0; r < 4; ++r) {
      #pragma unroll
      for (int d = 1; d < 16; d <<= 1)
        rs[r] += __shfl_xor(rs[r], d);
      lrow[r] = lrow[r] * alpha[r] + rs[r];
    }
    #pragma unroll
    for (int nt = 0; nt < 4; ++nt) {
      o[nt][0] *= alpha[0]; o[nt][1] *= alpha[1];
      o[nt][2] *= alpha[2]; o[nt][3] *= alpha[3];
    }
    #pragma unroll
    for (int nt = 0; nt < 4; ++nt)
      #pragma unroll
      for (int r = 0; r < 4; ++r)
        sh.Pl[w][lq * 4 + r][nt * 16 + l15] = f2bf(s[nt][r]);
    bf16x8 pa0 = *reinterpret_cast<const bf16x8*>(&sh.Pl[w][l15][8 * lq]);
    bf16x8 pa1 = *reinterpret_cast<const bf16x8*>(&sh.Pl[w][l15][32 + 8 * lq]);
    #pragma unroll
    for (int nt = 0; nt < 4; ++nt) {
      const short* vp = Vt + ((size_t)(b * DH + nt * 16 + l15)) * TT + k0 + 8 * lq;
      bf16x8 v0 = *reinterpret_cast<const bf16x8*>(vp);
      bf16x8 v1 = *reinterpret_cast<const bf16x8*>(vp + 32);
      o[nt] = __builtin_amdgcn_mfma_f32_16x16x32_bf16(pa0, v0, o[nt], 0, 0, 0);
      o[nt] = __builtin_amdgcn_mfma_f32_16x16x32_bf16(pa1, v1, o[nt], 0, 0, 0);
    }
  }
  __syncthreads();
  #pragma unroll
  for (int nt = 0; nt < 4; ++nt)
    #pragma unroll
    for (int r = 0; r < 4; ++r)
      sh.Om[w][lq * 4 + r][nt * 16 + l15] = o[nt][r];
  if (l15 == 0) {
    #pragma unroll
    for (int r = 0; r < 4; ++r) {
      Mm[w][lq * 4 + r] = mrow[r];
      Lm[w][lq * 4 + r] = lrow[r];
    }
  }
  __syncthreads();
  if (threadIdx.x < 16) {
    int row = threadIdx.x;
    float M = -1e30f;
    #pragma unroll
    for (int v = 0; v < 8; ++v) M = fmaxf(M, Mm[v][row]);
    float L = 0.f;
    #pragma unroll
    for (int v = 0; v < 8; ++v) {
      float sv = __expf(Mm[v][row] - M);
      Sc[v][row] = sv;
      L += Lm[v][row] * sv;
    }
    Linv[row] = 1.0f / L;
  }
  __syncthreads();
  int e = threadIdx.x;
  #pragma unroll
  for (int i = 0; i < 2; ++i, e += 512) {
    int row = e >> 6, col = e & 63;
    float val = 0.f;
    #pragma unroll
    for (int v = 0; v < 8; ++v) val += sh.Om[v][row][col] * Sc[v][row];
    out[((size_t)(b * TT + row0 + row)) * DH + col] = val * Linv[row];
  }
}

extern "C" void kernel_launch(void* const* d_in, const int* in_sizes, int n_in,
                              void* d_out, int out_size, void* d_ws, size_t ws_size,
                              hipStream_t stream) {
  const float* x  = (const float*)d_in[0];
  const float* Wq = (const float*)d_in[1];
  const float* Wk = (const float*)d_in[2];
  const float* Wv = (const float*)d_in[3];
  float* out = (float*)d_out;
  char* ws = (char*)d_ws;
  // ws: Qb 2MB | Kb 2MB | Vt 2MB | Wt 0.4MB | ... | abl junk @16MB,@20MB
  short* Qb = (short*)(ws);
  short* Kb = (short*)(ws + (2ull << 20));
  short* Vt = (short*)(ws + (4ull << 20));
  short* Wt = (short*)(ws + (6ull << 20));
  float* j1 = (float*)(ws + (16ull << 20));
  float* j2 = (float*)(ws + (20ull << 20));

  convw_kernel<<<dim3(768), dim3(256), 0, stream>>>(Wq, Wk, Wv, Wt);
  proj_kernel<<<dim3(256), dim3(512), 0, stream>>>(x, Wt, Qb, Kb, Vt);
  flash_abl<1><<<dim3(1024), dim3(512), 0, stream>>>(Qb, Kb, j1);
  flash_abl<2><<<dim3(1024), dim3(512), 0, stream>>>(Qb, Kb, j2);
  flash_kernel<<<dim3(1024), dim3(512), 0, stream>>>(Qb, Kb, Vt, out);
}